// Round 2
// baseline (28222.650 us; speedup 1.0000x reference)
//
#include <hip/hip_runtime.h>
#include <math.h>

// Applies to the whole file: no automatic FMA contraction. Explicit fmaf()
// calls below remain fused — this only pins the numpy-emulation arithmetic
// (square-then-add, subtract-then-add) to exact f32 rounding sequences.
#pragma clang fp contract(off)

#define N_ROWS 32768
#define DIM    256
#define K_EMB  8192

// ---------------------------------------------------------------------------
// numpy pairwise_sum emulation for one 128-element block of squares.
// Matches numpy's FLOAT_pairwise_sum unrolled branch exactly:
//   r[0..7] = a[0..7]; for i=8..120 step 8: r[j]+=a[i+j];
//   res = ((r0+r1)+(r2+r3))+((r4+r5)+(r6+r7))
// contract(off): square must round BEFORE the add (numpy builds x**2 temp).
// ---------------------------------------------------------------------------
__device__ __forceinline__ float np_pw128_sumsq(const float* __restrict__ a) {
  float r0 = a[0]*a[0], r1 = a[1]*a[1], r2 = a[2]*a[2], r3 = a[3]*a[3];
  float r4 = a[4]*a[4], r5 = a[5]*a[5], r6 = a[6]*a[6], r7 = a[7]*a[7];
  for (int i = 8; i < 128; i += 8) {
    r0 += a[i+0]*a[i+0];
    r1 += a[i+1]*a[i+1];
    r2 += a[i+2]*a[i+2];
    r3 += a[i+3]*a[i+3];
    r4 += a[i+4]*a[i+4];
    r5 += a[i+5]*a[i+5];
    r6 += a[i+6]*a[i+6];
    r7 += a[i+7]*a[i+7];
  }
  return ((r0+r1)+(r2+r3))+((r4+r5)+(r6+r7));
}

// A[row] = np.sum(src[row]**2) for n=256: pairwise splits 256 -> 128+128
__global__ __launch_bounds__(256) void vq_sumsq(const float* __restrict__ src,
                                                float* __restrict__ dst,
                                                int nrows) {
  int row = blockIdx.x * 256 + threadIdx.x;
  if (row >= nrows) return;
  const float* a = src + (size_t)row * DIM;
  float s0 = np_pw128_sumsq(a);
  float s1 = np_pw128_sumsq(a + 128);
  dst[row] = s0 + s1;
}

// ---------------------------------------------------------------------------
// Main argmin kernel. Block = 256 threads, 64 rows/block.
//   lane mapping: rl = tid>>2 (row within block), cg = tid&3 (code group)
//   X tile staged in LDS, XOR-swizzled at float4 granularity so the
//   uniform-k / varying-row ds_read_b128 is conflict-free.
//   Per tile of 16 codes each thread owns 4 sequential-k fmaf chains
//   (exact OpenBLAS-style accumulation order), then
//   d = (A - 2*b) + C  emulating numpy's two roundings, argmin with
//   first-index tie-break (strict < on ascending j; (d,j)-lex combine).
// ---------------------------------------------------------------------------
__global__ __launch_bounds__(256) void vq_argmin(const float* __restrict__ X,
                                                 const float* __restrict__ E,
                                                 const float* __restrict__ A,
                                                 const float* __restrict__ C,
                                                 int* __restrict__ idx_out,
                                                 float* __restrict__ idxf_out) {
  __shared__ float4 xs4[64 * 64];   // 64 rows x 64 float4 = 64 KiB
  const int tid  = threadIdx.x;
  const int rl   = tid >> 2;        // 0..63
  const int cg   = tid & 3;         // 0..3
  const int row0 = blockIdx.x * 64;

  // stage X tile, swizzled: xs4[r*64 + (kb ^ (r&7))]
  const float4* Xg = (const float4*)(X + (size_t)row0 * DIM);
  for (int it = 0; it < 16; ++it) {
    int f4 = tid + it * 256;        // 0..4095
    float4 v = Xg[f4];
    int r  = f4 >> 6;
    int kb = f4 & 63;
    xs4[r * 64 + (kb ^ (r & 7))] = v;
  }
  __syncthreads();

  const float a_r = A[row0 + rl];
  const int   swq = rl & 7;
  const float4* xrow = xs4 + rl * 64;

  float bd = INFINITY;
  int   bj = 0x7fffffff;

  for (int tile = 0; tile < K_EMB; tile += 16) {
    const int j0 = tile + cg * 4;
    const float4* e0 = (const float4*)(E + (size_t)(j0 + 0) * DIM);
    const float4* e1 = (const float4*)(E + (size_t)(j0 + 1) * DIM);
    const float4* e2 = (const float4*)(E + (size_t)(j0 + 2) * DIM);
    const float4* e3 = (const float4*)(E + (size_t)(j0 + 3) * DIM);
    float acc0 = 0.f, acc1 = 0.f, acc2 = 0.f, acc3 = 0.f;
#pragma unroll 4
    for (int kb = 0; kb < 64; ++kb) {
      const float4 xv = xrow[kb ^ swq];          // k = 4*kb .. 4*kb+3
      const float4 q0 = e0[kb];
      const float4 q1 = e1[kb];
      const float4 q2 = e2[kb];
      const float4 q3 = e3[kb];
      acc0 = fmaf(xv.x, q0.x, acc0); acc0 = fmaf(xv.y, q0.y, acc0);
      acc0 = fmaf(xv.z, q0.z, acc0); acc0 = fmaf(xv.w, q0.w, acc0);
      acc1 = fmaf(xv.x, q1.x, acc1); acc1 = fmaf(xv.y, q1.y, acc1);
      acc1 = fmaf(xv.z, q1.z, acc1); acc1 = fmaf(xv.w, q1.w, acc1);
      acc2 = fmaf(xv.x, q2.x, acc2); acc2 = fmaf(xv.y, q2.y, acc2);
      acc2 = fmaf(xv.z, q2.z, acc2); acc2 = fmaf(xv.w, q2.w, acc2);
      acc3 = fmaf(xv.x, q3.x, acc3); acc3 = fmaf(xv.y, q3.y, acc3);
      acc3 = fmaf(xv.z, q3.z, acc3); acc3 = fmaf(xv.w, q3.w, acc3);
    }
    // d = fl( fl(A - 2B) + C ): 2*acc exact (power of two scale)
    const float d0 = (a_r - 2.0f * acc0) + C[j0 + 0];
    const float d1 = (a_r - 2.0f * acc1) + C[j0 + 1];
    const float d2 = (a_r - 2.0f * acc2) + C[j0 + 2];
    const float d3 = (a_r - 2.0f * acc3) + C[j0 + 3];
    if (d0 < bd) { bd = d0; bj = j0 + 0; }   // ascending j: strict < keeps
    if (d1 < bd) { bd = d1; bj = j0 + 1; }   // first occurrence of the min
    if (d2 < bd) { bd = d2; bj = j0 + 2; }
    if (d3 < bd) { bd = d3; bj = j0 + 3; }
  }

  // combine the 4 lanes (same row) lexicographically on (d, j)
  for (int m = 1; m < 4; m <<= 1) {
    float od = __shfl_xor(bd, m);
    int   oj = __shfl_xor(bj, m);
    if (od < bd || (od == bd && oj < bj)) { bd = od; bj = oj; }
  }
  if (cg == 0) {
    int row = row0 + rl;
    idx_out[row]  = bj;
    idxf_out[row] = (float)bj;
  }
}

// ---------------------------------------------------------------------------
// quantized_st = fl(x + fl(q - x)); per-block f64 partial of sum (q-x)^2
// ---------------------------------------------------------------------------
__global__ __launch_bounds__(256) void vq_quant(const float* __restrict__ X,
                                                const float* __restrict__ E,
                                                const int* __restrict__ idx,
                                                float* __restrict__ out_qst,
                                                double* __restrict__ partials) {
  int gid  = blockIdx.x * 256 + threadIdx.x;   // 0 .. 2,097,151
  int base = gid * 4;
  int row  = base >> 8;
  int k    = base & 255;
  int j    = idx[row];
  const float4 xv = *(const float4*)(X + (size_t)base);
  const float4 ev = *(const float4*)(E + (size_t)j * DIM + k);
  float4 o;
  float d0 = ev.x - xv.x, d1 = ev.y - xv.y, d2 = ev.z - xv.z, d3 = ev.w - xv.w;
  o.x = xv.x + d0; o.y = xv.y + d1; o.z = xv.z + d2; o.w = xv.w + d3;
  double s = (double)d0 * d0 + (double)d1 * d1 + (double)d2 * d2 + (double)d3 * d3;
  *(float4*)(out_qst + (size_t)base) = o;

  for (int m = 32; m; m >>= 1) s += __shfl_xor(s, m);
  __shared__ double wsum[4];
  int lane = threadIdx.x & 63, w = threadIdx.x >> 6;
  if (lane == 0) wsum[w] = s;
  __syncthreads();
  if (threadIdx.x == 0)
    partials[blockIdx.x] = (wsum[0] + wsum[1]) + (wsum[2] + wsum[3]);
}

__global__ void vq_zero(unsigned* counts) {
  int i = blockIdx.x * 256 + threadIdx.x;
  if (i < K_EMB) counts[i] = 0u;
}

__global__ void vq_hist(const int* __restrict__ idx, unsigned* __restrict__ counts) {
  int i = blockIdx.x * 256 + threadIdx.x;
  if (i < N_ROWS) atomicAdd(&counts[idx[i]], 1u);
}

// loss + perplexity epilogue (single block)
__global__ __launch_bounds__(256) void vq_scalars(const double* __restrict__ partials,
                                                  const unsigned* __restrict__ counts,
                                                  float* __restrict__ out_loss,
                                                  float* __restrict__ out_perp) {
  __shared__ double red[256];
  int t = threadIdx.x;
  double s = 0.0;
  for (int i = t; i < 8192; i += 256) s += partials[i];
  red[t] = s;
  __syncthreads();
  for (int o = 128; o; o >>= 1) { if (t < o) red[t] += red[t + o]; __syncthreads(); }
  double mse = red[0] / (double)((size_t)N_ROWS * DIM);
  __syncthreads();

  double p = 0.0;
  for (int i = t; i < K_EMB; i += 256) {
    double pr = (double)counts[i] / (double)N_ROWS;
    p += pr * log(pr + 1e-10);
  }
  red[t] = p;
  __syncthreads();
  for (int o = 128; o; o >>= 1) { if (t < o) red[t] += red[t + o]; __syncthreads(); }
  if (t == 0) {
    float m = (float)mse;                 // q_latent_loss == e_latent_loss
    out_loss[0] = m + 0.25f * m;          // + COMMITMENT_COST * e_latent
    out_perp[0] = (float)exp(-red[0]);
  }
}

extern "C" void kernel_launch(void* const* d_in, const int* in_sizes, int n_in,
                              void* d_out, int out_size, void* d_ws, size_t ws_size,
                              hipStream_t stream) {
  const float* X = (const float*)d_in[0];   // [32768, 256]
  const float* E = (const float*)d_in[1];   // [8192, 256]
  float* out  = (float*)d_out;
  float* qst  = out;                         // 8,388,608
  float* loss = out + 8388608;               // 1
  float* perp = out + 8388609;               // 1
  float* idxf = out + 8388610;               // 32768 (indices as float)

  // workspace layout (floats): A[32768] | C[8192] | idx[32768] | counts[8192]
  // then doubles: partials[8192] at byte offset 327680. Total 384 KiB.
  float*    A        = (float*)d_ws;
  float*    C        = A + 32768;
  int*      idx      = (int*)(A + 40960);
  unsigned* counts   = (unsigned*)(A + 73728);
  double*   partials = (double*)((char*)d_ws + 327680);

  vq_zero  <<<32,   256, 0, stream>>>(counts);
  vq_sumsq <<<128,  256, 0, stream>>>(X, A, N_ROWS);
  vq_sumsq <<<32,   256, 0, stream>>>(E, C, K_EMB);
  vq_argmin<<<512,  256, 0, stream>>>(X, E, A, C, idx, idxf);
  vq_quant <<<8192, 256, 0, stream>>>(X, E, idx, qst, partials);
  vq_hist  <<<128,  256, 0, stream>>>(idx, counts);
  vq_scalars<<<1,   256, 0, stream>>>(partials, counts, loss, perp);
}